// Round 9
// baseline (4242.126 us; speedup 1.0000x reference)
//
#include <hip/hip_runtime.h>

#define BB   128   // batch
#define TT   256   // time steps
#define HH   512   // hidden
#define G4   2048  // 4*H
#define OUTN 1024  // output vocab
#define NBLK 256
#define NTHR 512

// LDS geometry
#define WSTRIDE 520                 // padded col-major stride (elems)
#define WREG    (16 * WSTRIDE)      // one weight region: 16 gate-cols x 520
#define ZOFF    (6 * WREG * 2)      // byte offset of z scratch = 99840
#define ZSTRIDE 20                  // padded z row stride (floats)
#define LDS_BYTES (ZOFF + 2 * 64 * ZSTRIDE * 4)   // 110080

// workspace layout (bytes): [4096,..) arrival flags (u32 every 64B),
// [24576,..) release flags, [32768,..) H buffers
#define FLAG_OFF  4096
#define FLAG_STRIDE 16              // u32 elements -> 64 B apart
#define REL_OFF   24576
#define H_OFF     32768

typedef __attribute__((ext_vector_type(8))) short  v8s;   // 8 bf16 (4 VGPRs)
typedef __attribute__((ext_vector_type(4))) float  v4f;   // MFMA acc

#define MFMA_(a,b,c) __builtin_amdgcn_mfma_f32_16x16x32_bf16(a, b, c, 0, 0, 0)

__device__ __forceinline__ float sigmoidf_(float x) {
    return 1.0f / (1.0f + __expf(-x));
}
__device__ __forceinline__ unsigned short f2bf_rn(float f) {
    unsigned u = __float_as_uint(f);
    unsigned r = u + 0x7fffu + ((u >> 16) & 1u);
    return (unsigned short)(r >> 16);
}
__device__ __forceinline__ float bf2f(unsigned short h) {
    return __uint_as_float(((unsigned)h) << 16);
}

// One asm load, SHARED base register pair + immediate offset
#define ISSUE_OFF(dst, base, OFFB) \
    asm volatile("global_load_dwordx4 %0, %1, off offset:" #OFFB \
                 : "=v"(dst) : "v"(base) : "memory")

#define I16(f, b) do { \
    ISSUE_OFF(f[0],  b, 0);    ISSUE_OFF(f[1],  b, 64); \
    ISSUE_OFF(f[2],  b, 128);  ISSUE_OFF(f[3],  b, 192); \
    ISSUE_OFF(f[4],  b, 256);  ISSUE_OFF(f[5],  b, 320); \
    ISSUE_OFF(f[6],  b, 384);  ISSUE_OFF(f[7],  b, 448); \
    ISSUE_OFF(f[8],  b, 512);  ISSUE_OFF(f[9],  b, 576); \
    ISSUE_OFF(f[10], b, 640);  ISSUE_OFF(f[11], b, 704); \
    ISSUE_OFF(f[12], b, 768);  ISSUE_OFF(f[13], b, 832); \
    ISSUE_OFF(f[14], b, 896);  ISSUE_OFF(f[15], b, 960); \
} while (0)

#define WAITCNT_VM0 do { \
    asm volatile("s_waitcnt vmcnt(0)" ::: "memory"); \
    __builtin_amdgcn_sched_barrier(0); \
} while (0)

__global__ void __launch_bounds__(NTHR, 1)
deeplog_kernel(const int* __restrict__ x,
               const float* __restrict__ Wx1, const float* __restrict__ Wh1, const float* __restrict__ b1,
               const float* __restrict__ Wx2, const float* __restrict__ Wh2, const float* __restrict__ b2,
               const float* __restrict__ Wd,  const float* __restrict__ bd,
               float* __restrict__ out, void* __restrict__ wsv)
{
    extern __shared__ char smem[];
    unsigned short* wlds = (unsigned short*)smem;            // 6 x [16][520] bf16 weight regions
    float* zlds = (float*)(smem + ZOFF);                     // [2][64][20] f32 preactivations

    char* wsb = (char*)wsv;
    unsigned* flags    = (unsigned*)(wsb + FLAG_OFF);        // arrival flag[i] at flags[i*FLAG_STRIDE]
    unsigned* releases = (unsigned*)(wsb + REL_OFF);         // release[rb] at releases[rb*16]
    unsigned short* Hbase = (unsigned short*)(wsb + H_OFF);
    unsigned short* H1hi[2] = { Hbase,           Hbase + 65536 };
    unsigned short* H1lo[2] = { Hbase + 131072,  Hbase + 196608 };
    unsigned short* H2hi[2] = { Hbase + 262144,  Hbase + 327680 };
    unsigned short* H2lo[2] = { Hbase + 393216,  Hbase + 458752 };
    // u32 views for pair-packed write-through stores (same memory, same layout)
    unsigned* H1hi32[2] = { (unsigned*)H1hi[0], (unsigned*)H1hi[1] };
    unsigned* H1lo32[2] = { (unsigned*)H1lo[0], (unsigned*)H1lo[1] };
    unsigned* H2hi32[2] = { (unsigned*)H2hi[0], (unsigned*)H2hi[1] };
    unsigned* H2lo32[2] = { (unsigned*)H2lo[0], (unsigned*)H2lo[1] };

    const int bid  = blockIdx.x;
    const int tid  = threadIdx.x;
    const int rb   = bid >> 7;           // 0..1 row-group
    const int cb   = bid & 127;          // 0..127 col-group
    const int b0   = rb * 64;            // first batch row of block
    const int n0   = cb * 4;             // first hidden unit of block
    const int fbase = rb << 7;           // flag base of my barrier group (0 or 128)

    const int lane = tid & 63;
    const int wv   = tid >> 6;           // wave 0..7
    const int isL2 = (wv >= 4);          // waves 4-7 -> layer 2
    const int wt   = isL2 ? (wv - 4) : wv;       // row-tile within block (16 rows each)
    const int kgrp = (lane >> 4) * 8;            // k-slot group for A/B fragments
    const int colb = (lane & 15) * WSTRIDE + kgrp;
    const int aoff = ((b0 + wt * 16 + (lane & 15)) << 9) + kgrp;  // row*512 + kgrp

    // gate-stage ownership: thread t -> layer (t>>8), cell (row=(t&255)>>2, nl=t&3)
    const int Lme  = tid >> 8;           // == isL2
    const int u    = tid & 255;
    const int grow = u >> 2;             // 0..63 local row
    const int nl   = u & 3;
    const int rowg = b0 + grow;          // global batch row
    const int n    = n0 + nl;            // global hidden unit

    // ---- one-time: stage split-bf16 weights to LDS (col-major, padded) ----
    for (int m = 0; m < 3; ++m) {
        const float* Wsrc = (m == 0) ? Wh1 : (m == 1) ? Wx2 : Wh2;
        unsigned short* dhi = wlds + (2 * m) * WREG;
        unsigned short* dlo = wlds + (2 * m + 1) * WREG;
        for (int i = tid; i < 8192; i += NTHR) {
            int k = i >> 4, c = i & 15;
            float v = Wsrc[(size_t)k * G4 + ((c >> 2) << 9) + n0 + (c & 3)];
            unsigned short hi = f2bf_rn(v);
            unsigned short lo = f2bf_rn(v - bf2f(hi));
            dhi[c * WSTRIDE + k] = hi;
            dlo[c * WSTRIDE + k] = lo;
        }
    }
    __syncthreads();

    const unsigned short* wh1h = wlds;
    const unsigned short* wh1l = wlds + WREG;
    const unsigned short* wx2h = wlds + 2 * WREG;
    const unsigned short* wx2l = wlds + 3 * WREG;
    const unsigned short* wh2h = wlds + 4 * WREG;
    const unsigned short* wh2l = wlds + 5 * WREG;

    // hoisted biases for owned cell (gate order i,f,g,o)
    const float* bsrc = Lme ? b2 : b1;
    float bias0 = bsrc[n], bias1 = bsrc[HH + n], bias2 = bsrc[2 * HH + n], bias3 = bsrc[3 * HH + n];

    float c_state = 0.0f;
    unsigned tgt = 1;

    #pragma unroll 1
    for (int p = 0; p <= TT; ++p) {
        // prefetch one-hot row of Wx1 for the gate stage
        float wx0 = 0.f, wx1v = 0.f, wx2v = 0.f, wx3v = 0.f;
        if (Lme == 0 && p < TT) {
            int xr = x[rowg * TT + p];
            const float* wxp = Wx1 + (size_t)xr * G4 + n;
            wx0 = wxp[0]; wx1v = wxp[HH]; wx2v = wxp[2 * HH]; wx3v = wxp[3 * HH];
        }

        // ---- MFMA GEMMs (unchanged from round 8: 32-frag clusters, g2 drip) ----
        const int q1 = (p - 1) & 1;   // parity holding h1(p-1)
        const int q2 = p & 1;         // parity holding h2(p-2)
        if (!isL2) {
            if (p < TT) {
                v4f accP = {0.f, 0.f, 0.f, 0.f}, accQ = {0.f, 0.f, 0.f, 0.f};
                v8s ah[16], al[16];
                const unsigned short* p1h = H1hi[q1] + aoff;
                const unsigned short* p1l = H1lo[q1] + aoff;
                I16(ah, p1h);
                I16(al, p1l);
                WAITCNT_VM0;
                const unsigned short* B1h = wh1h + colb;
                const unsigned short* B1l = wh1l + colb;
                #pragma unroll
                for (int kk = 0; kk < 16; ++kk) {
                    v8s bh = *(const v8s*)(B1h + kk * 32);
                    v8s bl = *(const v8s*)(B1l + kk * 32);
                    accP = MFMA_(ah[kk], bh, accP);
                    accQ = MFMA_(ah[kk], bl, accQ);
                    accP = MFMA_(al[kk], bl, accP);
                    accQ = MFMA_(al[kk], bh, accQ);
                }
                int r0 = wt * 16 + ((lane >> 4) << 2);
                #pragma unroll
                for (int q = 0; q < 4; ++q)
                    zlds[(r0 + q) * ZSTRIDE + (lane & 15)] = accP[q] + accQ[q];
            }
        } else {
            if (p >= 1) {
                v4f accP = {0.f, 0.f, 0.f, 0.f}, accQ = {0.f, 0.f, 0.f, 0.f};
                v8s a1h[16], a1l[16], a2h[16], a2l[16];
                const unsigned short* p1h = H1hi[q1] + aoff;
                const unsigned short* p1l = H1lo[q1] + aoff;
                const unsigned short* p2h = H2hi[q2] + aoff;
                const unsigned short* p2l = H2lo[q2] + aoff;
                I16(a1h, p1h);
                I16(a1l, p1l);
                WAITCNT_VM0;
                const unsigned short* B1h = wx2h + colb;
                const unsigned short* B1l = wx2l + colb;
                #define G1STEP(k, OFF) do { \
                    v8s bh = *(const v8s*)(B1h + (k) * 32); \
                    v8s bl = *(const v8s*)(B1l + (k) * 32); \
                    accP = MFMA_(a1h[k], bh, accP); \
                    accQ = MFMA_(a1h[k], bl, accQ); \
                    accP = MFMA_(a1l[k], bl, accP); \
                    accQ = MFMA_(a1l[k], bh, accQ); \
                    ISSUE_OFF(a2h[k], p2h, OFF); \
                    ISSUE_OFF(a2l[k], p2l, OFF); \
                } while (0)
                G1STEP(0, 0);    G1STEP(1, 64);   G1STEP(2, 128);  G1STEP(3, 192);
                G1STEP(4, 256);  G1STEP(5, 320);  G1STEP(6, 384);  G1STEP(7, 448);
                G1STEP(8, 512);  G1STEP(9, 576);  G1STEP(10, 640); G1STEP(11, 704);
                G1STEP(12, 768); G1STEP(13, 832); G1STEP(14, 896); G1STEP(15, 960);
                #undef G1STEP
                WAITCNT_VM0;
                const unsigned short* B2h = wh2h + colb;
                const unsigned short* B2l = wh2l + colb;
                #pragma unroll
                for (int kk = 0; kk < 16; ++kk) {
                    v8s bh = *(const v8s*)(B2h + kk * 32);
                    v8s bl = *(const v8s*)(B2l + kk * 32);
                    accP = MFMA_(a2h[kk], bh, accP);
                    accQ = MFMA_(a2h[kk], bl, accQ);
                    accP = MFMA_(a2l[kk], bl, accP);
                    accQ = MFMA_(a2l[kk], bh, accQ);
                }
                int r0 = wt * 16 + ((lane >> 4) << 2);
                #pragma unroll
                for (int q = 0; q < 4; ++q)
                    zlds[64 * ZSTRIDE + (r0 + q) * ZSTRIDE + (lane & 15)] = accP[q] + accQ[q];
            }
        }
        __syncthreads();

        // ---- gates: thread owns one (layer, row, n) cell; c-state in register.
        // h published as WRITE-THROUGH agent atomics (u32 = two adjacent n). ----
        bool act = (Lme == 0) ? (p < TT) : (p >= 1);
        if (act) {
            const float* zrow = zlds + Lme * (64 * ZSTRIDE) + grow * ZSTRIDE;
            float z0 = zrow[nl]      + bias0;
            float z1 = zrow[4 + nl]  + bias1;
            float z2 = zrow[8 + nl]  + bias2;
            float z3 = zrow[12 + nl] + bias3;
            if (Lme == 0) { z0 += wx0; z1 += wx1v; z2 += wx2v; z3 += wx3v; }
            float gi = sigmoidf_(z0);
            float gf = sigmoidf_(z1);
            float gg = tanhf(z2);
            float go = sigmoidf_(z3);
            c_state  = gf * c_state + gi * gg;
            float h  = go * tanhf(c_state);
            unsigned hhi = f2bf_rn(h);
            unsigned hlo = f2bf_rn(h - bf2f((unsigned short)hhi));
            unsigned ph = (unsigned)__shfl_xor((int)hhi, 1, 64);
            unsigned pl = (unsigned)__shfl_xor((int)hlo, 1, 64);
            if ((nl & 1) == 0) {
                unsigned hw = (hhi & 0xffffu) | (ph << 16);   // low half = even n
                unsigned lw = (hlo & 0xffffu) | (pl << 16);
                unsigned *dsthi, *dstlo;
                if (Lme == 0) { dsthi = H1hi32[p & 1];       dstlo = H1lo32[p & 1]; }
                else          { dsthi = H2hi32[(p - 1) & 1]; dstlo = H2lo32[(p - 1) & 1]; }
                int idx = rowg * 256 + (n >> 1);
                __hip_atomic_store(dsthi + idx, hw, __ATOMIC_RELAXED, __HIP_MEMORY_SCOPE_AGENT);
                __hip_atomic_store(dstlo + idx, lw, __ATOMIC_RELAXED, __HIP_MEMORY_SCOPE_AGENT);
            }
        }

        // ---- HIERARCHICAL grid barrier (round-9 change: kill the poll storm).
        // Arrival: per-block flag store (parallel, unchanged).
        // Detection: ONLY block fbase scans its group's 128 flags (128 lanes).
        // Release: scanner posts release[rb]; everyone else polls ONE address
        // with ONE lane. Old scheme: 32768 L2-bypass pollers ~ 4 TB/s of L3
        // traffic contending with the critical-path h loads (rounds 6-8: phase
        // time invariant at 16 us across 3 different gemm structures). ----
        __syncthreads();
        if (tid == 0) {
            asm volatile("s_waitcnt vmcnt(0)" ::: "memory");
            __hip_atomic_store(&flags[bid * FLAG_STRIDE], tgt,
                               __ATOMIC_RELAXED, __HIP_MEMORY_SCOPE_AGENT);
        }
        if (bid == fbase) {
            // scanner: lane t watches group flag t
            if (tid < 128) {
                while (__hip_atomic_load(&flags[(fbase + tid) * FLAG_STRIDE],
                                         __ATOMIC_RELAXED, __HIP_MEMORY_SCOPE_AGENT) < tgt)
                    __builtin_amdgcn_s_sleep(1);
            }
            __syncthreads();   // all scans observed (block-uniform branch: safe)
            if (tid == 0)
                __hip_atomic_store(&releases[rb * 16], tgt,
                                   __ATOMIC_RELEASE, __HIP_MEMORY_SCOPE_AGENT);
        }
        if (tid == 0) {
            while (__hip_atomic_load(&releases[rb * 16],
                                     __ATOMIC_RELAXED, __HIP_MEMORY_SCOPE_AGENT) < tgt)
                __builtin_amdgcn_s_sleep(2);
            if (p == TT) {   // final: head reads both row-groups
                while (__hip_atomic_load(&releases[(1 - rb) * 16],
                                         __ATOMIC_RELAXED, __HIP_MEMORY_SCOPE_AGENT) < tgt)
                    __builtin_amdgcn_s_sleep(2);
            }
            // acquire-inv: next phase's cached h reads must refetch remote data
            (void)__hip_atomic_load(&releases[rb * 16],
                                    __ATOMIC_ACQUIRE, __HIP_MEMORY_SCOPE_AGENT);
        }
        __syncthreads();
        ++tgt;
    }

    // ---- final dense + softmax: block b handles output row b ----
    if (bid < BB) {
        const unsigned short* h2hi = H2hi[(TT - 1) & 1] + (size_t)bid * HH;
        const unsigned short* h2lo = H2lo[(TT - 1) & 1] + (size_t)bid * HH;
        float* hrow = zlds;            // 512 floats
        float* red  = zlds + HH;       // 512 floats
        hrow[tid] = bf2f(h2hi[tid]) + bf2f(h2lo[tid]);
        __syncthreads();

        float a0 = bd[tid], a1 = bd[tid + 512];
        const float* w = Wd + tid;
        #pragma unroll 4
        for (int k = 0; k < HH; ++k) {
            float hv = hrow[k];
            a0 += hv * w[(size_t)k * OUTN];
            a1 += hv * w[(size_t)k * OUTN + 512];
        }

        red[tid] = fmaxf(a0, a1);
        __syncthreads();
        for (int s = NTHR / 2; s > 0; s >>= 1) {
            if (tid < s) red[tid] = fmaxf(red[tid], red[tid + s]);
            __syncthreads();
        }
        float M = red[0];
        __syncthreads();
        float e0 = __expf(a0 - M), e1 = __expf(a1 - M);
        red[tid] = e0 + e1;
        __syncthreads();
        for (int s = NTHR / 2; s > 0; s >>= 1) {
            if (tid < s) red[tid] += red[tid + s];
            __syncthreads();
        }
        float inv = 1.0f / red[0];
        out[(size_t)bid * OUTN + tid]       = e0 * inv;
        out[(size_t)bid * OUTN + tid + 512] = e1 * inv;
    }
}

extern "C" void kernel_launch(void* const* d_in, const int* in_sizes, int n_in,
                              void* d_out, int out_size, void* d_ws, size_t ws_size,
                              hipStream_t stream) {
    (void)in_sizes; (void)n_in; (void)out_size; (void)ws_size;

    const int*   x   = (const int*)  d_in[0];
    const float* Wx1 = (const float*)d_in[1];
    const float* Wh1 = (const float*)d_in[2];
    const float* b1  = (const float*)d_in[3];
    const float* Wx2 = (const float*)d_in[4];
    const float* Wh2 = (const float*)d_in[5];
    const float* b2  = (const float*)d_in[6];
    const float* Wd  = (const float*)d_in[7];
    const float* bd  = (const float*)d_in[8];
    float* out = (float*)d_out;
    void* ws   = d_ws;

    (void)hipFuncSetAttribute((const void*)deeplog_kernel,
                              hipFuncAttributeMaxDynamicSharedMemorySize, LDS_BYTES);

    // zero: arrival flags + release flags (poisoned 0xAA would satisfy >= tgt!) + h buffers
    size_t zero_bytes = H_OFF + (size_t)8 * BB * HH * sizeof(unsigned short);  // 1,081,344
    hipMemsetAsync(d_ws, 0, zero_bytes, stream);

    void* args[] = { &x, &Wx1, &Wh1, &b1, &Wx2, &Wh2, &b2, &Wd, &bd, &out, &ws };
    hipLaunchCooperativeKernel((const void*)deeplog_kernel,
                               dim3(NBLK), dim3(NTHR), args, LDS_BYTES, stream);
}

// Round 10
// 3880.201 us; speedup vs baseline: 1.0933x; 1.0933x over previous
//
#include <hip/hip_runtime.h>

#define BB   128   // batch
#define TT   256   // time steps
#define HH   512   // hidden
#define G4   2048  // 4*H
#define OUTN 1024  // output vocab
#define NBLK 256
#define NTHR 512

// LDS geometry
#define WSTRIDE 520                 // padded col-major stride (elems)
#define WREG    (16 * WSTRIDE)      // one weight region: 16 gate-cols x 520
#define ZOFF    (6 * WREG * 2)      // byte offset of z scratch = 99840
#define ZSTRIDE 20                  // padded z row stride (floats)
#define LDS_BYTES (ZOFF + 2 * 64 * ZSTRIDE * 4)   // 110080

// workspace layout (bytes): [4096,..) arrival flags (u32 every 64B),
// [24576,..) release flags, [32768,..) H buffers
#define FLAG_OFF  4096
#define FLAG_STRIDE 16              // u32 elements -> 64 B apart
#define REL_OFF   24576
#define H_OFF     32768

typedef __attribute__((ext_vector_type(8))) short  v8s;   // 8 bf16 (4 VGPRs)
typedef __attribute__((ext_vector_type(4))) float  v4f;   // MFMA acc

#define MFMA_(a,b,c) __builtin_amdgcn_mfma_f32_16x16x32_bf16(a, b, c, 0, 0, 0)

__device__ __forceinline__ float sigmoidf_(float x) {
    return 1.0f / (1.0f + __expf(-x));
}
__device__ __forceinline__ unsigned short f2bf_rn(float f) {
    unsigned u = __float_as_uint(f);
    unsigned r = u + 0x7fffu + ((u >> 16) & 1u);
    return (unsigned short)(r >> 16);
}
__device__ __forceinline__ float bf2f(unsigned short h) {
    return __uint_as_float(((unsigned)h) << 16);
}

// COHERENT asm load: sc0 sc1 bypass L1+L2 and read L3 directly (same semantics
// our relaxed-agent flag polls demonstrably have). Round-10 change: this
// replaces the per-phase ACQUIRE buffer_inv — 32 blocks/XCD serializing inv on
// one L2 was the 13 us/phase floor (phase time invariant across r6-r9's gemm
// and barrier-topology changes; r6's wbl2 removal = same mechanism, -7 us).
#define ISSUE_OFF(dst, base, OFFB) \
    asm volatile("global_load_dwordx4 %0, %1, off offset:" #OFFB " sc0 sc1" \
                 : "=v"(dst) : "v"(base) : "memory")

#define I16(f, b) do { \
    ISSUE_OFF(f[0],  b, 0);    ISSUE_OFF(f[1],  b, 64); \
    ISSUE_OFF(f[2],  b, 128);  ISSUE_OFF(f[3],  b, 192); \
    ISSUE_OFF(f[4],  b, 256);  ISSUE_OFF(f[5],  b, 320); \
    ISSUE_OFF(f[6],  b, 384);  ISSUE_OFF(f[7],  b, 448); \
    ISSUE_OFF(f[8],  b, 512);  ISSUE_OFF(f[9],  b, 576); \
    ISSUE_OFF(f[10], b, 640);  ISSUE_OFF(f[11], b, 704); \
    ISSUE_OFF(f[12], b, 768);  ISSUE_OFF(f[13], b, 832); \
    ISSUE_OFF(f[14], b, 896);  ISSUE_OFF(f[15], b, 960); \
} while (0)

#define WAITCNT_VM0 do { \
    asm volatile("s_waitcnt vmcnt(0)" ::: "memory"); \
    __builtin_amdgcn_sched_barrier(0); \
} while (0)

__global__ void __launch_bounds__(NTHR, 1)
deeplog_kernel(const int* __restrict__ x,
               const float* __restrict__ Wx1, const float* __restrict__ Wh1, const float* __restrict__ b1,
               const float* __restrict__ Wx2, const float* __restrict__ Wh2, const float* __restrict__ b2,
               const float* __restrict__ Wd,  const float* __restrict__ bd,
               float* __restrict__ out, void* __restrict__ wsv)
{
    extern __shared__ char smem[];
    unsigned short* wlds = (unsigned short*)smem;            // 6 x [16][520] bf16 weight regions
    float* zlds = (float*)(smem + ZOFF);                     // [2][64][20] f32 preactivations

    char* wsb = (char*)wsv;
    unsigned* flags    = (unsigned*)(wsb + FLAG_OFF);        // arrival flag[i] at flags[i*FLAG_STRIDE]
    unsigned* releases = (unsigned*)(wsb + REL_OFF);         // release[rb] at releases[rb*16]
    unsigned short* Hbase = (unsigned short*)(wsb + H_OFF);
    unsigned short* H1hi[2] = { Hbase,           Hbase + 65536 };
    unsigned short* H1lo[2] = { Hbase + 131072,  Hbase + 196608 };
    unsigned short* H2hi[2] = { Hbase + 262144,  Hbase + 327680 };
    unsigned short* H2lo[2] = { Hbase + 393216,  Hbase + 458752 };
    // u32 views for pair-packed write-through stores (same memory, same layout)
    unsigned* H1hi32[2] = { (unsigned*)H1hi[0], (unsigned*)H1hi[1] };
    unsigned* H1lo32[2] = { (unsigned*)H1lo[0], (unsigned*)H1lo[1] };
    unsigned* H2hi32[2] = { (unsigned*)H2hi[0], (unsigned*)H2hi[1] };
    unsigned* H2lo32[2] = { (unsigned*)H2lo[0], (unsigned*)H2lo[1] };

    const int bid  = blockIdx.x;
    const int tid  = threadIdx.x;
    const int rb   = bid >> 7;           // 0..1 row-group
    const int cb   = bid & 127;          // 0..127 col-group
    const int b0   = rb * 64;            // first batch row of block
    const int n0   = cb * 4;             // first hidden unit of block
    const int fbase = rb << 7;           // flag base of my barrier group (0 or 128)

    const int lane = tid & 63;
    const int wv   = tid >> 6;           // wave 0..7
    const int isL2 = (wv >= 4);          // waves 4-7 -> layer 2
    const int wt   = isL2 ? (wv - 4) : wv;       // row-tile within block (16 rows each)
    const int kgrp = (lane >> 4) * 8;            // k-slot group for A/B fragments
    const int colb = (lane & 15) * WSTRIDE + kgrp;
    const int aoff = ((b0 + wt * 16 + (lane & 15)) << 9) + kgrp;  // row*512 + kgrp

    // gate-stage ownership: thread t -> layer (t>>8), cell (row=(t&255)>>2, nl=t&3)
    const int Lme  = tid >> 8;           // == isL2
    const int u    = tid & 255;
    const int grow = u >> 2;             // 0..63 local row
    const int nl   = u & 3;
    const int rowg = b0 + grow;          // global batch row
    const int n    = n0 + nl;            // global hidden unit

    // ---- one-time: stage split-bf16 weights to LDS (col-major, padded) ----
    for (int m = 0; m < 3; ++m) {
        const float* Wsrc = (m == 0) ? Wh1 : (m == 1) ? Wx2 : Wh2;
        unsigned short* dhi = wlds + (2 * m) * WREG;
        unsigned short* dlo = wlds + (2 * m + 1) * WREG;
        for (int i = tid; i < 8192; i += NTHR) {
            int k = i >> 4, c = i & 15;
            float v = Wsrc[(size_t)k * G4 + ((c >> 2) << 9) + n0 + (c & 3)];
            unsigned short hi = f2bf_rn(v);
            unsigned short lo = f2bf_rn(v - bf2f(hi));
            dhi[c * WSTRIDE + k] = hi;
            dlo[c * WSTRIDE + k] = lo;
        }
    }
    __syncthreads();

    const unsigned short* wh1h = wlds;
    const unsigned short* wh1l = wlds + WREG;
    const unsigned short* wx2h = wlds + 2 * WREG;
    const unsigned short* wx2l = wlds + 3 * WREG;
    const unsigned short* wh2h = wlds + 4 * WREG;
    const unsigned short* wh2l = wlds + 5 * WREG;

    // hoisted biases for owned cell (gate order i,f,g,o)
    const float* bsrc = Lme ? b2 : b1;
    float bias0 = bsrc[n], bias1 = bsrc[HH + n], bias2 = bsrc[2 * HH + n], bias3 = bsrc[3 * HH + n];

    float c_state = 0.0f;
    unsigned tgt = 1;

    #pragma unroll 1
    for (int p = 0; p <= TT; ++p) {
        // prefetch one-hot row of Wx1 for the gate stage. These are plain cached
        // loads — with no per-phase inv, Wx1/x lines now stay warm in L2.
        float wx0 = 0.f, wx1v = 0.f, wx2v = 0.f, wx3v = 0.f;
        if (Lme == 0 && p < TT) {
            int xr = x[rowg * TT + p];
            const float* wxp = Wx1 + (size_t)xr * G4 + n;
            wx0 = wxp[0]; wx1v = wxp[HH]; wx2v = wxp[2 * HH]; wx3v = wxp[3 * HH];
        }

        // ---- MFMA GEMMs (r8 structure; A-loads now sc0 sc1 coherent) ----
        const int q1 = (p - 1) & 1;   // parity holding h1(p-1)
        const int q2 = p & 1;         // parity holding h2(p-2)
        if (!isL2) {
            if (p < TT) {
                v4f accP = {0.f, 0.f, 0.f, 0.f}, accQ = {0.f, 0.f, 0.f, 0.f};
                v8s ah[16], al[16];
                const unsigned short* p1h = H1hi[q1] + aoff;
                const unsigned short* p1l = H1lo[q1] + aoff;
                I16(ah, p1h);
                I16(al, p1l);
                WAITCNT_VM0;
                const unsigned short* B1h = wh1h + colb;
                const unsigned short* B1l = wh1l + colb;
                #pragma unroll
                for (int kk = 0; kk < 16; ++kk) {
                    v8s bh = *(const v8s*)(B1h + kk * 32);
                    v8s bl = *(const v8s*)(B1l + kk * 32);
                    accP = MFMA_(ah[kk], bh, accP);
                    accQ = MFMA_(ah[kk], bl, accQ);
                    accP = MFMA_(al[kk], bl, accP);
                    accQ = MFMA_(al[kk], bh, accQ);
                }
                int r0 = wt * 16 + ((lane >> 4) << 2);
                #pragma unroll
                for (int q = 0; q < 4; ++q)
                    zlds[(r0 + q) * ZSTRIDE + (lane & 15)] = accP[q] + accQ[q];
            }
        } else {
            if (p >= 1) {
                v4f accP = {0.f, 0.f, 0.f, 0.f}, accQ = {0.f, 0.f, 0.f, 0.f};
                v8s a1h[16], a1l[16], a2h[16], a2l[16];
                const unsigned short* p1h = H1hi[q1] + aoff;
                const unsigned short* p1l = H1lo[q1] + aoff;
                const unsigned short* p2h = H2hi[q2] + aoff;
                const unsigned short* p2l = H2lo[q2] + aoff;
                I16(a1h, p1h);
                I16(a1l, p1l);
                WAITCNT_VM0;
                const unsigned short* B1h = wx2h + colb;
                const unsigned short* B1l = wx2l + colb;
                #define G1STEP(k, OFF) do { \
                    v8s bh = *(const v8s*)(B1h + (k) * 32); \
                    v8s bl = *(const v8s*)(B1l + (k) * 32); \
                    accP = MFMA_(a1h[k], bh, accP); \
                    accQ = MFMA_(a1h[k], bl, accQ); \
                    accP = MFMA_(a1l[k], bl, accP); \
                    accQ = MFMA_(a1l[k], bh, accQ); \
                    ISSUE_OFF(a2h[k], p2h, OFF); \
                    ISSUE_OFF(a2l[k], p2l, OFF); \
                } while (0)
                G1STEP(0, 0);    G1STEP(1, 64);   G1STEP(2, 128);  G1STEP(3, 192);
                G1STEP(4, 256);  G1STEP(5, 320);  G1STEP(6, 384);  G1STEP(7, 448);
                G1STEP(8, 512);  G1STEP(9, 576);  G1STEP(10, 640); G1STEP(11, 704);
                G1STEP(12, 768); G1STEP(13, 832); G1STEP(14, 896); G1STEP(15, 960);
                #undef G1STEP
                WAITCNT_VM0;
                const unsigned short* B2h = wh2h + colb;
                const unsigned short* B2l = wh2l + colb;
                #pragma unroll
                for (int kk = 0; kk < 16; ++kk) {
                    v8s bh = *(const v8s*)(B2h + kk * 32);
                    v8s bl = *(const v8s*)(B2l + kk * 32);
                    accP = MFMA_(a2h[kk], bh, accP);
                    accQ = MFMA_(a2h[kk], bl, accQ);
                    accP = MFMA_(a2l[kk], bl, accP);
                    accQ = MFMA_(a2l[kk], bh, accQ);
                }
                int r0 = wt * 16 + ((lane >> 4) << 2);
                #pragma unroll
                for (int q = 0; q < 4; ++q)
                    zlds[64 * ZSTRIDE + (r0 + q) * ZSTRIDE + (lane & 15)] = accP[q] + accQ[q];
            }
        }
        __syncthreads();

        // ---- gates: thread owns one (layer, row, n) cell; c-state in register.
        // h published as WRITE-THROUGH agent atomics (u32 = two adjacent n). ----
        bool act = (Lme == 0) ? (p < TT) : (p >= 1);
        if (act) {
            const float* zrow = zlds + Lme * (64 * ZSTRIDE) + grow * ZSTRIDE;
            float z0 = zrow[nl]      + bias0;
            float z1 = zrow[4 + nl]  + bias1;
            float z2 = zrow[8 + nl]  + bias2;
            float z3 = zrow[12 + nl] + bias3;
            if (Lme == 0) { z0 += wx0; z1 += wx1v; z2 += wx2v; z3 += wx3v; }
            float gi = sigmoidf_(z0);
            float gf = sigmoidf_(z1);
            float gg = tanhf(z2);
            float go = sigmoidf_(z3);
            c_state  = gf * c_state + gi * gg;
            float h  = go * tanhf(c_state);
            unsigned hhi = f2bf_rn(h);
            unsigned hlo = f2bf_rn(h - bf2f((unsigned short)hhi));
            unsigned ph = (unsigned)__shfl_xor((int)hhi, 1, 64);
            unsigned pl = (unsigned)__shfl_xor((int)hlo, 1, 64);
            if ((nl & 1) == 0) {
                unsigned hw = (hhi & 0xffffu) | (ph << 16);   // low half = even n
                unsigned lw = (hlo & 0xffffu) | (pl << 16);
                unsigned *dsthi, *dstlo;
                if (Lme == 0) { dsthi = H1hi32[p & 1];       dstlo = H1lo32[p & 1]; }
                else          { dsthi = H2hi32[(p - 1) & 1]; dstlo = H2lo32[(p - 1) & 1]; }
                int idx = rowg * 256 + (n >> 1);
                __hip_atomic_store(dsthi + idx, hw, __ATOMIC_RELAXED, __HIP_MEMORY_SCOPE_AGENT);
                __hip_atomic_store(dstlo + idx, lw, __ATOMIC_RELAXED, __HIP_MEMORY_SCOPE_AGENT);
            }
        }

        // ---- hierarchical grid barrier — now with ZERO cache-maintenance ops.
        // Chain: write-through h stores (drained at syncthreads) -> relaxed flag
        // (L3) -> scan -> relaxed release (L3) -> poll -> sc0sc1 h loads (L3).
        // Single serialization point is L3; no inv, no wbl2, anywhere. ----
        __syncthreads();
        if (tid == 0) {
            asm volatile("s_waitcnt vmcnt(0)" ::: "memory");
            __hip_atomic_store(&flags[bid * FLAG_STRIDE], tgt,
                               __ATOMIC_RELAXED, __HIP_MEMORY_SCOPE_AGENT);
        }
        if (bid == fbase) {
            // scanner: lane t watches group flag t
            if (tid < 128) {
                while (__hip_atomic_load(&flags[(fbase + tid) * FLAG_STRIDE],
                                         __ATOMIC_RELAXED, __HIP_MEMORY_SCOPE_AGENT) < tgt)
                    __builtin_amdgcn_s_sleep(1);
            }
            __syncthreads();   // all scans observed (block-uniform branch: safe)
            if (tid == 0)
                __hip_atomic_store(&releases[rb * 16], tgt,
                                   __ATOMIC_RELAXED, __HIP_MEMORY_SCOPE_AGENT);
        }
        if (tid == 0) {
            while (__hip_atomic_load(&releases[rb * 16],
                                     __ATOMIC_RELAXED, __HIP_MEMORY_SCOPE_AGENT) < tgt)
                __builtin_amdgcn_s_sleep(2);
            if (p == TT) {   // final: head reads both row-groups
                while (__hip_atomic_load(&releases[(1 - rb) * 16],
                                         __ATOMIC_RELAXED, __HIP_MEMORY_SCOPE_AGENT) < tgt)
                    __builtin_amdgcn_s_sleep(2);
            }
        }
        __syncthreads();
        ++tgt;
    }

    // ---- final dense + softmax: block b handles output row b.
    // h2 read via coherent atomic loads (no inv exists to freshen L2). ----
    if (bid < BB) {
        float* hrow = zlds;            // 512 floats
        float* red  = zlds + HH;       // 512 floats
        if (tid < 256) {
            unsigned hw = __hip_atomic_load(H2hi32[(TT - 1) & 1] + bid * 256 + tid,
                                            __ATOMIC_RELAXED, __HIP_MEMORY_SCOPE_AGENT);
            unsigned lw = __hip_atomic_load(H2lo32[(TT - 1) & 1] + bid * 256 + tid,
                                            __ATOMIC_RELAXED, __HIP_MEMORY_SCOPE_AGENT);
            hrow[2 * tid]     = bf2f((unsigned short)(hw & 0xffffu)) + bf2f((unsigned short)(lw & 0xffffu));
            hrow[2 * tid + 1] = bf2f((unsigned short)(hw >> 16))     + bf2f((unsigned short)(lw >> 16));
        }
        __syncthreads();

        float a0 = bd[tid], a1 = bd[tid + 512];
        const float* w = Wd + tid;
        #pragma unroll 4
        for (int k = 0; k < HH; ++k) {
            float hv = hrow[k];
            a0 += hv * w[(size_t)k * OUTN];
            a1 += hv * w[(size_t)k * OUTN + 512];
        }

        red[tid] = fmaxf(a0, a1);
        __syncthreads();
        for (int s = NTHR / 2; s > 0; s >>= 1) {
            if (tid < s) red[tid] = fmaxf(red[tid], red[tid + s]);
            __syncthreads();
        }
        float M = red[0];
        __syncthreads();
        float e0 = __expf(a0 - M), e1 = __expf(a1 - M);
        red[tid] = e0 + e1;
        __syncthreads();
        for (int s = NTHR / 2; s > 0; s >>= 1) {
            if (tid < s) red[tid] += red[tid + s];
            __syncthreads();
        }
        float inv = 1.0f / red[0];
        out[(size_t)bid * OUTN + tid]       = e0 * inv;
        out[(size_t)bid * OUTN + tid + 512] = e1 * inv;
    }
}

extern "C" void kernel_launch(void* const* d_in, const int* in_sizes, int n_in,
                              void* d_out, int out_size, void* d_ws, size_t ws_size,
                              hipStream_t stream) {
    (void)in_sizes; (void)n_in; (void)out_size; (void)ws_size;

    const int*   x   = (const int*)  d_in[0];
    const float* Wx1 = (const float*)d_in[1];
    const float* Wh1 = (const float*)d_in[2];
    const float* b1  = (const float*)d_in[3];
    const float* Wx2 = (const float*)d_in[4];
    const float* Wh2 = (const float*)d_in[5];
    const float* b2  = (const float*)d_in[6];
    const float* Wd  = (const float*)d_in[7];
    const float* bd  = (const float*)d_in[8];
    float* out = (float*)d_out;
    void* ws   = d_ws;

    (void)hipFuncSetAttribute((const void*)deeplog_kernel,
                              hipFuncAttributeMaxDynamicSharedMemorySize, LDS_BYTES);

    // zero: arrival flags + release flags (poisoned 0xAA would satisfy >= tgt!) + h buffers
    size_t zero_bytes = H_OFF + (size_t)8 * BB * HH * sizeof(unsigned short);  // 1,081,344
    hipMemsetAsync(d_ws, 0, zero_bytes, stream);

    void* args[] = { &x, &Wx1, &Wh1, &b1, &Wx2, &Wh2, &b2, &Wd, &bd, &out, &ws };
    hipLaunchCooperativeKernel((const void*)deeplog_kernel,
                               dim3(NBLK), dim3(NTHR), args, LDS_BYTES, stream);
}

// Round 11
// 3064.839 us; speedup vs baseline: 1.3841x; 1.2660x over previous
//
#include <hip/hip_runtime.h>

#define BB   128   // batch
#define TT   256   // time steps
#define HH   512   // hidden
#define G4   2048  // 4*H
#define OUTN 1024  // output vocab
#define NBLK 256
#define NTHR 512

// LDS geometry
#define WSTRIDE 520                 // padded col-major stride (elems)
#define WREG    (16 * WSTRIDE)      // one weight region: 16 gate-cols x 520
#define ZOFF    (6 * WREG * 2)      // byte offset of z scratch = 99840
#define ZSTRIDE 20                  // padded z row stride (floats)
// z regions: z1 [64][20] | z2x [64][20] | z2h [64][20]
#define LDS_BYTES (ZOFF + 3 * 64 * ZSTRIDE * 4)   // 99840 + 15360 = 115200

// workspace layout (bytes): [4096,..) arrival flags (u32 every 64B), [32768,..) H buffers
#define FLAG_OFF  4096
#define FLAG_STRIDE 16              // u32 elements -> 64 B apart
#define H_OFF     32768

typedef __attribute__((ext_vector_type(8))) short  v8s;   // 8 bf16 (4 VGPRs)
typedef __attribute__((ext_vector_type(4))) float  v4f;   // MFMA acc

#define MFMA_(a,b,c) __builtin_amdgcn_mfma_f32_16x16x32_bf16(a, b, c, 0, 0, 0)

__device__ __forceinline__ float sigmoidf_(float x) {
    return 1.0f / (1.0f + __expf(-x));
}
__device__ __forceinline__ unsigned short f2bf_rn(float f) {
    unsigned u = __float_as_uint(f);
    unsigned r = u + 0x7fffu + ((u >> 16) & 1u);
    return (unsigned short)(r >> 16);
}
__device__ __forceinline__ float bf2f(unsigned short h) {
    return __uint_as_float(((unsigned)h) << 16);
}

// COHERENT asm load (sc0 sc1 -> L3-direct; no cache maintenance needed anywhere)
#define ISSUE_OFF(dst, base, OFFB) \
    asm volatile("global_load_dwordx4 %0, %1, off offset:" #OFFB " sc0 sc1" \
                 : "=v"(dst) : "v"(base) : "memory")

#define I16(f, b) do { \
    ISSUE_OFF(f[0],  b, 0);    ISSUE_OFF(f[1],  b, 64); \
    ISSUE_OFF(f[2],  b, 128);  ISSUE_OFF(f[3],  b, 192); \
    ISSUE_OFF(f[4],  b, 256);  ISSUE_OFF(f[5],  b, 320); \
    ISSUE_OFF(f[6],  b, 384);  ISSUE_OFF(f[7],  b, 448); \
    ISSUE_OFF(f[8],  b, 512);  ISSUE_OFF(f[9],  b, 576); \
    ISSUE_OFF(f[10], b, 640);  ISSUE_OFF(f[11], b, 704); \
    ISSUE_OFF(f[12], b, 768);  ISSUE_OFF(f[13], b, 832); \
    ISSUE_OFF(f[14], b, 896);  ISSUE_OFF(f[15], b, 960); \
} while (0)

#define WAITCNT_VM0 do { \
    asm volatile("s_waitcnt vmcnt(0)" ::: "memory"); \
    __builtin_amdgcn_sched_barrier(0); \
} while (0)

// Split-bf16 gemm with 4 INDEPENDENT accumulators (dep distance 2 -> 4: MFMA
// latency stalls eliminated; final z sums all four, same value as P+Q).
__device__ __forceinline__ void gemm_4acc(const v8s ah[16], const v8s al[16],
    const unsigned short* __restrict__ Bh, const unsigned short* __restrict__ Bl,
    float* __restrict__ zout, int r0, int col)
{
    v4f c0 = {0.f,0.f,0.f,0.f}, c1 = {0.f,0.f,0.f,0.f};
    v4f c2 = {0.f,0.f,0.f,0.f}, c3 = {0.f,0.f,0.f,0.f};
    #pragma unroll
    for (int kk = 0; kk < 16; ++kk) {
        v8s bh = *(const v8s*)(Bh + kk * 32);
        v8s bl = *(const v8s*)(Bl + kk * 32);
        c0 = MFMA_(ah[kk], bh, c0);
        c1 = MFMA_(ah[kk], bl, c1);
        c2 = MFMA_(al[kk], bl, c2);
        c3 = MFMA_(al[kk], bh, c3);
    }
    #pragma unroll
    for (int q = 0; q < 4; ++q)
        zout[(r0 + q) * ZSTRIDE + col] = c0[q] + c1[q] + c2[q] + c3[q];
}

__global__ void __launch_bounds__(NTHR, 1)
deeplog_kernel(const int* __restrict__ x,
               const float* __restrict__ Wx1, const float* __restrict__ Wh1, const float* __restrict__ b1,
               const float* __restrict__ Wx2, const float* __restrict__ Wh2, const float* __restrict__ b2,
               const float* __restrict__ Wd,  const float* __restrict__ bd,
               float* __restrict__ out, void* __restrict__ wsv)
{
    extern __shared__ char smem[];
    unsigned short* wlds = (unsigned short*)smem;            // 6 x [16][520] bf16 weight regions
    float* zlds = (float*)(smem + ZOFF);                     // z1 | z2x | z2h, each [64][20]

    char* wsb = (char*)wsv;
    unsigned* flags = (unsigned*)(wsb + FLAG_OFF);           // flag[i] at flags[i*FLAG_STRIDE]
    unsigned short* Hbase = (unsigned short*)(wsb + H_OFF);
    unsigned short* H1hi[2] = { Hbase,           Hbase + 65536 };
    unsigned short* H1lo[2] = { Hbase + 131072,  Hbase + 196608 };
    unsigned short* H2hi[2] = { Hbase + 262144,  Hbase + 327680 };
    unsigned short* H2lo[2] = { Hbase + 393216,  Hbase + 458752 };
    unsigned* H1hi32[2] = { (unsigned*)H1hi[0], (unsigned*)H1hi[1] };
    unsigned* H1lo32[2] = { (unsigned*)H1lo[0], (unsigned*)H1lo[1] };
    unsigned* H2hi32[2] = { (unsigned*)H2hi[0], (unsigned*)H2hi[1] };
    unsigned* H2lo32[2] = { (unsigned*)H2lo[0], (unsigned*)H2lo[1] };

    const int bid  = blockIdx.x;
    const int tid  = threadIdx.x;
    const int rb   = bid >> 7;           // 0..1 row-group
    const int cb   = bid & 127;          // 0..127 col-group
    const int b0   = rb * 64;            // first batch row of block
    const int n0   = cb * 4;             // first hidden unit of block
    const int fbase = rb << 7;           // flag base of my barrier group (0 or 128)

    const int lane = tid & 63;
    const int wv   = tid >> 6;           // wave 0..7
    const int isL2 = (wv >= 4);          // waves 4-7: H2 / z2h duty
    const int wt   = isL2 ? (wv - 4) : wv;       // row-tile within block (16 rows each)
    const int kgrp = (lane >> 4) * 8;            // k-slot group for A/B fragments
    const int colb = (lane & 15) * WSTRIDE + kgrp;
    const int aoff = ((b0 + wt * 16 + (lane & 15)) << 9) + kgrp;  // row*512 + kgrp
    const int r0g  = wt * 16 + ((lane >> 4) << 2);                // z-row base for D-frag
    const int colz = lane & 15;

    // gate-stage ownership: thread t -> layer (t>>8), cell (row=(t&255)>>2, nl=t&3)
    const int Lme  = tid >> 8;
    const int u    = tid & 255;
    const int grow = u >> 2;             // 0..63 local row
    const int nl   = u & 3;
    const int rowg = b0 + grow;          // global batch row
    const int n    = n0 + nl;            // global hidden unit

    // ---- one-time: stage split-bf16 weights to LDS (col-major, padded) ----
    for (int m = 0; m < 3; ++m) {
        const float* Wsrc = (m == 0) ? Wh1 : (m == 1) ? Wx2 : Wh2;
        unsigned short* dhi = wlds + (2 * m) * WREG;
        unsigned short* dlo = wlds + (2 * m + 1) * WREG;
        for (int i = tid; i < 8192; i += NTHR) {
            int k = i >> 4, c = i & 15;
            float v = Wsrc[(size_t)k * G4 + ((c >> 2) << 9) + n0 + (c & 3)];
            unsigned short hi = f2bf_rn(v);
            unsigned short lo = f2bf_rn(v - bf2f(hi));
            dhi[c * WSTRIDE + k] = hi;
            dlo[c * WSTRIDE + k] = lo;
        }
    }
    __syncthreads();

    const unsigned short* wh1h = wlds;
    const unsigned short* wh1l = wlds + WREG;
    const unsigned short* wx2h = wlds + 2 * WREG;
    const unsigned short* wx2l = wlds + 3 * WREG;
    const unsigned short* wh2h = wlds + 4 * WREG;
    const unsigned short* wh2l = wlds + 5 * WREG;

    // hoisted biases for owned cell (gate order i,f,g,o)
    const float* bsrc = Lme ? b2 : b1;
    float bias0 = bsrc[n], bias1 = bsrc[HH + n], bias2 = bsrc[2 * HH + n], bias3 = bsrc[3 * HH + n];

    float c_state = 0.0f;
    unsigned tgt = 1;

    #pragma unroll 1
    for (int p = 0; p <= TT; ++p) {
        // prefetch one-hot row of Wx1 for the gate stage (plain cached loads;
        // Wx1/x stay warm in L2 — no inv exists anymore)
        float wx0 = 0.f, wx1v = 0.f, wx2v = 0.f, wx3v = 0.f;
        if (Lme == 0 && p < TT) {
            int xr = x[rowg * TT + p];
            const float* wxp = Wx1 + (size_t)xr * G4 + n;
            wx0 = wxp[0]; wx1v = wxp[HH]; wx2v = wxp[2 * HH]; wx3v = wxp[3 * HH];
        }

        // ---- GEMMs. ROUND-11 RESTRUCTURE: L1 waves own the H1 fragments and
        // compute BOTH h1@Wh1 (z1) and h1@Wx2 (z2x) from one load — L2 waves
        // load only H2 (z2h). Per-block A-traffic 384 KB -> 256 KB (the
        // invariant-15us diagnosis: per-CU L3 read bandwidth is the floor). ----
        const int q1 = (p - 1) & 1;   // parity holding h1(p-1)
        const int q2 = p & 1;         // parity holding h2(p-2)
        if (!isL2) {
            v8s ah[16], al[16];
            const unsigned short* p1h = H1hi[q1] + aoff;
            const unsigned short* p1l = H1lo[q1] + aoff;
            I16(ah, p1h);
            I16(al, p1l);
            WAITCNT_VM0;
            if (p < TT)
                gemm_4acc(ah, al, wh1h + colb, wh1l + colb, zlds, r0g, colz);
            if (p >= 1)
                gemm_4acc(ah, al, wx2h + colb, wx2l + colb, zlds + 64 * ZSTRIDE, r0g, colz);
        } else {
            if (p >= 1) {
                v8s ah[16], al[16];
                const unsigned short* p2h = H2hi[q2] + aoff;
                const unsigned short* p2l = H2lo[q2] + aoff;
                I16(ah, p2h);
                I16(al, p2l);
                WAITCNT_VM0;
                gemm_4acc(ah, al, wh2h + colb, wh2l + colb, zlds + 128 * ZSTRIDE, r0g, colz);
            }
        }
        __syncthreads();

        // ---- gates: thread owns one (layer, row, n) cell; c-state in register.
        // Layer-2 preactivation = z2x + z2h (two partials from two wave-groups).
        // h published as WRITE-THROUGH agent atomics (u32 = two adjacent n). ----
        bool act = (Lme == 0) ? (p < TT) : (p >= 1);
        if (act) {
            float z0, z1, z2, z3;
            if (Lme == 0) {
                const float* zr = zlds + grow * ZSTRIDE;
                z0 = zr[nl]      + bias0 + wx0;
                z1 = zr[4 + nl]  + bias1 + wx1v;
                z2 = zr[8 + nl]  + bias2 + wx2v;
                z3 = zr[12 + nl] + bias3 + wx3v;
            } else {
                const float* zx = zlds + 64 * ZSTRIDE  + grow * ZSTRIDE;
                const float* zh = zlds + 128 * ZSTRIDE + grow * ZSTRIDE;
                z0 = zx[nl]      + zh[nl]      + bias0;
                z1 = zx[4 + nl]  + zh[4 + nl]  + bias1;
                z2 = zx[8 + nl]  + zh[8 + nl]  + bias2;
                z3 = zx[12 + nl] + zh[12 + nl] + bias3;
            }
            float gi = sigmoidf_(z0);
            float gf = sigmoidf_(z1);
            float gg = tanhf(z2);
            float go = sigmoidf_(z3);
            c_state  = gf * c_state + gi * gg;
            float h  = go * tanhf(c_state);
            unsigned hhi = f2bf_rn(h);
            unsigned hlo = f2bf_rn(h - bf2f((unsigned short)hhi));
            unsigned ph = (unsigned)__shfl_xor((int)hhi, 1, 64);
            unsigned pl = (unsigned)__shfl_xor((int)hlo, 1, 64);
            if ((nl & 1) == 0) {
                unsigned hw = (hhi & 0xffffu) | (ph << 16);   // low half = even n
                unsigned lw = (hlo & 0xffffu) | (pl << 16);
                unsigned *dsthi, *dstlo;
                if (Lme == 0) { dsthi = H1hi32[p & 1];       dstlo = H1lo32[p & 1]; }
                else          { dsthi = H2hi32[(p - 1) & 1]; dstlo = H2lo32[(p - 1) & 1]; }
                int idx = rowg * 256 + (n >> 1);
                __hip_atomic_store(dsthi + idx, hw, __ATOMIC_RELAXED, __HIP_MEMORY_SCOPE_AGENT);
                __hip_atomic_store(dstlo + idx, lw, __ATOMIC_RELAXED, __HIP_MEMORY_SCOPE_AGENT);
            }
        }

        // ---- FLAT 2-hop grid barrier (store flag -> direct poll); zero cache
        // maintenance (write-through stores + sc0sc1 reads carry coherence) ----
        __syncthreads();
        if (tid == 0) {
            asm volatile("s_waitcnt vmcnt(0)" ::: "memory");
            __hip_atomic_store(&flags[bid * FLAG_STRIDE], tgt,
                               __ATOMIC_RELAXED, __HIP_MEMORY_SCOPE_AGENT);
        }
        {
            const int nf = (p == TT) ? NBLK : 128;
            const int f0 = (p == TT) ? 0    : fbase;
            if (tid < nf) {
                while (__hip_atomic_load(&flags[(f0 + tid) * FLAG_STRIDE],
                                         __ATOMIC_RELAXED, __HIP_MEMORY_SCOPE_AGENT) < tgt)
                    __builtin_amdgcn_s_sleep(1);
            }
        }
        __syncthreads();
        ++tgt;
    }

    // ---- final dense + softmax: block b handles output row b (coherent reads) ----
    if (bid < BB) {
        float* hrow = zlds;            // 512 floats
        float* red  = zlds + HH;       // 512 floats
        if (tid < 256) {
            unsigned hw = __hip_atomic_load(H2hi32[(TT - 1) & 1] + bid * 256 + tid,
                                            __ATOMIC_RELAXED, __HIP_MEMORY_SCOPE_AGENT);
            unsigned lw = __hip_atomic_load(H2lo32[(TT - 1) & 1] + bid * 256 + tid,
                                            __ATOMIC_RELAXED, __HIP_MEMORY_SCOPE_AGENT);
            hrow[2 * tid]     = bf2f((unsigned short)(hw & 0xffffu)) + bf2f((unsigned short)(lw & 0xffffu));
            hrow[2 * tid + 1] = bf2f((unsigned short)(hw >> 16))     + bf2f((unsigned short)(lw >> 16));
        }
        __syncthreads();

        float a0 = bd[tid], a1 = bd[tid + 512];
        const float* w = Wd + tid;
        #pragma unroll 4
        for (int k = 0; k < HH; ++k) {
            float hv = hrow[k];
            a0 += hv * w[(size_t)k * OUTN];
            a1 += hv * w[(size_t)k * OUTN + 512];
        }

        red[tid] = fmaxf(a0, a1);
        __syncthreads();
        for (int s = NTHR / 2; s > 0; s >>= 1) {
            if (tid < s) red[tid] = fmaxf(red[tid], red[tid + s]);
            __syncthreads();
        }
        float M = red[0];
        __syncthreads();
        float e0 = __expf(a0 - M), e1 = __expf(a1 - M);
        red[tid] = e0 + e1;
        __syncthreads();
        for (int s = NTHR / 2; s > 0; s >>= 1) {
            if (tid < s) red[tid] += red[tid + s];
            __syncthreads();
        }
        float inv = 1.0f / red[0];
        out[(size_t)bid * OUTN + tid]       = e0 * inv;
        out[(size_t)bid * OUTN + tid + 512] = e1 * inv;
    }
}

extern "C" void kernel_launch(void* const* d_in, const int* in_sizes, int n_in,
                              void* d_out, int out_size, void* d_ws, size_t ws_size,
                              hipStream_t stream) {
    (void)in_sizes; (void)n_in; (void)out_size; (void)ws_size;

    const int*   x   = (const int*)  d_in[0];
    const float* Wx1 = (const float*)d_in[1];
    const float* Wh1 = (const float*)d_in[2];
    const float* b1  = (const float*)d_in[3];
    const float* Wx2 = (const float*)d_in[4];
    const float* Wh2 = (const float*)d_in[5];
    const float* b2  = (const float*)d_in[6];
    const float* Wd  = (const float*)d_in[7];
    const float* bd  = (const float*)d_in[8];
    float* out = (float*)d_out;
    void* ws   = d_ws;

    (void)hipFuncSetAttribute((const void*)deeplog_kernel,
                              hipFuncAttributeMaxDynamicSharedMemorySize, LDS_BYTES);

    // zero: flags (poisoned 0xAA would satisfy >= tgt!) + h buffers
    size_t zero_bytes = H_OFF + (size_t)8 * BB * HH * sizeof(unsigned short);  // 1,081,344
    hipMemsetAsync(d_ws, 0, zero_bytes, stream);

    void* args[] = { &x, &Wx1, &Wh1, &b1, &Wx2, &Wh2, &b2, &Wd, &bd, &out, &ws };
    hipLaunchCooperativeKernel((const void*)deeplog_kernel,
                               dim3(NBLK), dim3(NTHR), args, LDS_BYTES, stream);
}